// Round 17
// baseline (128.936 us; speedup 1.0000x reference)
//
#include <hip/hip_runtime.h>

#define NROWS 131072
#define D 64
#define K 1024

typedef __attribute__((ext_vector_type(8))) short short8;
typedef __attribute__((ext_vector_type(4))) float f32x4;
typedef unsigned int u32;

// ws layout (bytes):
//   [0, 131072)        ehT  ushort[1024][64]  bf16 codebook, [code][d]
//   [131072, 135168)   e2g  float[1024]       = -0.5*||e_k||^2
//   [135168, 139264)   hist int[1024]
//   [139264, 143360)   wavesum float[256]  (one per score block)

__device__ __forceinline__ unsigned short f2bf_rne(float f) {
    u32 u = __float_as_uint(f);
    u += 0x7fff + ((u >> 16) & 1);   // round-to-nearest-even
    return (unsigned short)(u >> 16);
}

__device__ __forceinline__ float b2f(short s) {
    return __uint_as_float(((u32)(unsigned short)s) << 16);
}

// 16 blocks x 256 threads: block handles 64 codes, thread = (code, d-quarter).
__global__ __launch_bounds__(256) void prep_kernel(const float* __restrict__ E,
                                                   unsigned short* __restrict__ ehT,
                                                   float* __restrict__ e2g,
                                                   int* __restrict__ hist) {
    __shared__ float ps[4][64];
    const int lane = threadIdx.x & 63;          // code offset within block
    const int w = threadIdx.x >> 6;             // d-quarter 0..3
    const int k = blockIdx.x * 64 + lane;
    float s = 0.f;
#pragma unroll
    for (int half = 0; half < 2; ++half) {
        short8 h8;
#pragma unroll
        for (int j = 0; j < 8; ++j) {
            float v = E[(w * 16 + half * 8 + j) * K + k];   // coalesced across lanes
            s = fmaf(v, v, s);
            h8[j] = (short)f2bf_rne(v);
        }
        *(short8*)(ehT + (size_t)k * D + w * 16 + half * 8) = h8;
    }
    ps[w][lane] = s;
    __syncthreads();
    if (w == 0) e2g[k] = -0.5f * (ps[0][lane] + ps[1][lane] + ps[2][lane] + ps[3][lane]);
    if (threadIdx.x < 64) hist[blockIdx.x * 64 + threadIdx.x] = 0;
}

// R22: wave-desynchronized, merge-free structure — the first variant that
// removes the session's one untested invariant (cross-wave coupling).
// Evidence: ~80% of score time is stall (issue work ~8us vs 50us measured)
// and every 49-57us variant shared the mrg->barrier->merge phase chain that
// stalls all 16 waves TOGETHER. Here: wave owns 32 ROWS (in registers, 16
// VGPR), the ENTIRE bf16 codebook (128KB) + e2 (4KB) lives in LDS (160KB/CU,
// frag-order = conflict-free like R7's xbuf). After ONE barrier, each wave
// sweeps 64 code-tiles from LDS with zero barriers, zero cross-wave traffic:
// the quad-shfl reduce leaves EVERY lane holding its own row's packed argmax
// -> no mrg, no idxl, no merge waves. 16 waves free-run and desynchronize;
// stalls interleave instead of aligning. Avoids R18's traps: B stays in
// registers (no LDS re-read), no in-loop global prefetch (LDS only).
// Numerics: identical operands/MFMA chain/packed score|code values; max over
// distinct packed values is order-independent -> same argmax, q, hist.
// absmax canary: exactly 0.4326172.
__global__ __launch_bounds__(1024) void score_kernel(const float* __restrict__ X,
                                                     const unsigned short* __restrict__ ehT,
                                                     const float* __restrict__ e2g,
                                                     int* __restrict__ hist,
                                                     float* __restrict__ wavesum,
                                                     float* __restrict__ q) {
    extern __shared__ char lds[];              // 135168 B: codebook + e2
    unsigned short* cbuf = (unsigned short*)lds;          // 128 KB frag-order
    float* e2s = (float*)(lds + 131072);                  // 4 KB
    __shared__ float redL[16];

    const int tid = threadIdx.x;
    const int wave = tid >> 6;
    const int lane = tid & 63;
    const int quad = lane >> 4;
    const int lc = lane & 15;
    const size_t row0 = (size_t)blockIdx.x * 512 + (size_t)wave * 32;

    // ---- stage codebook into LDS, frag order: 16B unit u = (tile=u>>7,
    // ks=(u>>6)&1, q=(u>>4)&3, lc=u&15) holds ehT[tile*16+lc][ks*32+q*8 ..+8].
    // LDS writes linear in u (conflict-free); global reads L2/L3-hot.
#pragma unroll
    for (int j = 0; j < 8; ++j) {
        int u = tid + j * 1024;
        int tile = u >> 7, r = u & 127;
        int ks = r >> 6, qq = (r >> 4) & 3, ll = r & 15;
        *(short8*)(cbuf + (size_t)u * 8) =
            *(const short8*)(ehT + ((size_t)(tile * 16 + ll) << 6) + ks * 32 + qq * 8);
    }
    e2s[tid] = e2g[tid];

    // ---- X fragments in registers: lane (quad,lc) holds rows row0+lc and
    // row0+16+lc, d-slices [quad*8..+8) (ks0) and [32+quad*8..+8) (ks1),
    // trunc-packed bf16 (same values as R7's staged xbuf).
    short8 b00, b01, b10, b11;
    {
        const float* xa = X + (row0 + lc) * D + quad * 8;
        const float* xb = X + (row0 + 16 + lc) * D + quad * 8;
        float4 v0, v1;
        union { u32 u[4]; short8 v; } pk;
        v0 = *(const float4*)(xa);      v1 = *(const float4*)(xa + 4);
        pk.u[0] = __builtin_amdgcn_perm(__float_as_uint(v0.y), __float_as_uint(v0.x), 0x07060302);
        pk.u[1] = __builtin_amdgcn_perm(__float_as_uint(v0.w), __float_as_uint(v0.z), 0x07060302);
        pk.u[2] = __builtin_amdgcn_perm(__float_as_uint(v1.y), __float_as_uint(v1.x), 0x07060302);
        pk.u[3] = __builtin_amdgcn_perm(__float_as_uint(v1.w), __float_as_uint(v1.z), 0x07060302);
        b00 = pk.v;
        v0 = *(const float4*)(xa + 32); v1 = *(const float4*)(xa + 36);
        pk.u[0] = __builtin_amdgcn_perm(__float_as_uint(v0.y), __float_as_uint(v0.x), 0x07060302);
        pk.u[1] = __builtin_amdgcn_perm(__float_as_uint(v0.w), __float_as_uint(v0.z), 0x07060302);
        pk.u[2] = __builtin_amdgcn_perm(__float_as_uint(v1.y), __float_as_uint(v1.x), 0x07060302);
        pk.u[3] = __builtin_amdgcn_perm(__float_as_uint(v1.w), __float_as_uint(v1.z), 0x07060302);
        b01 = pk.v;
        v0 = *(const float4*)(xb);      v1 = *(const float4*)(xb + 4);
        pk.u[0] = __builtin_amdgcn_perm(__float_as_uint(v0.y), __float_as_uint(v0.x), 0x07060302);
        pk.u[1] = __builtin_amdgcn_perm(__float_as_uint(v0.w), __float_as_uint(v0.z), 0x07060302);
        pk.u[2] = __builtin_amdgcn_perm(__float_as_uint(v1.y), __float_as_uint(v1.x), 0x07060302);
        pk.u[3] = __builtin_amdgcn_perm(__float_as_uint(v1.w), __float_as_uint(v1.z), 0x07060302);
        b10 = pk.v;
        v0 = *(const float4*)(xb + 32); v1 = *(const float4*)(xb + 36);
        pk.u[0] = __builtin_amdgcn_perm(__float_as_uint(v0.y), __float_as_uint(v0.x), 0x07060302);
        pk.u[1] = __builtin_amdgcn_perm(__float_as_uint(v0.w), __float_as_uint(v0.z), 0x07060302);
        pk.u[2] = __builtin_amdgcn_perm(__float_as_uint(v1.y), __float_as_uint(v1.x), 0x07060302);
        pk.u[3] = __builtin_amdgcn_perm(__float_as_uint(v1.w), __float_as_uint(v1.z), 0x07060302);
        b11 = pk.v;
    }

    __syncthreads();   // THE only inter-wave barrier before the end

    // ---- free-running sweep: 64 code-tiles, software-pipelined from LDS ----
    const char* cb = (const char*)cbuf;
    const int aoff = quad * 256 + lc * 16;
    float bt0 = -3.4e38f, bt1 = -3.4e38f;
    short8 a0 = *(const short8*)(cb + aoff);
    short8 a1 = *(const short8*)(cb + aoff + 1024);
    f32x4 e2v = *(const f32x4*)(e2s + quad * 4);

#pragma unroll 4
    for (int tile = 0; tile < 64; ++tile) {
        const int nt = (tile + 1) & 63;        // wraps at 63: valid read, unused
        short8 a0n = *(const short8*)(cb + nt * 2048 + aoff);
        short8 a1n = *(const short8*)(cb + nt * 2048 + aoff + 1024);
        f32x4 e2n = *(const f32x4*)(e2s + nt * 16 + quad * 4);

        f32x4 acc0 = __builtin_amdgcn_mfma_f32_16x16x32_bf16(a0, b00, e2v, 0, 0, 0);
        acc0 = __builtin_amdgcn_mfma_f32_16x16x32_bf16(a1, b01, acc0, 0, 0, 0);
        f32x4 acc1 = __builtin_amdgcn_mfma_f32_16x16x32_bf16(a0, b10, e2v, 0, 0, 0);
        acc1 = __builtin_amdgcn_mfma_f32_16x16x32_bf16(a1, b11, acc1, 0, 0, 0);

        const u32 cbid = (u32)(tile * 16 + quad * 4);
        // acc0[r] = score(code = cbid+r, row = row0+lc); acc1: row0+16+lc
        float p0 = __uint_as_float((__float_as_uint(acc0[0]) & 0xFFFFFC00u) | (cbid + 0));
        float p1 = __uint_as_float((__float_as_uint(acc0[1]) & 0xFFFFFC00u) | (cbid + 1));
        float p2 = __uint_as_float((__float_as_uint(acc0[2]) & 0xFFFFFC00u) | (cbid + 2));
        float p3 = __uint_as_float((__float_as_uint(acc0[3]) & 0xFFFFFC00u) | (cbid + 3));
        bt0 = fmaxf(bt0, fmaxf(p0, p1));   // v_max3
        bt0 = fmaxf(bt0, fmaxf(p2, p3));
        p0 = __uint_as_float((__float_as_uint(acc1[0]) & 0xFFFFFC00u) | (cbid + 0));
        p1 = __uint_as_float((__float_as_uint(acc1[1]) & 0xFFFFFC00u) | (cbid + 1));
        p2 = __uint_as_float((__float_as_uint(acc1[2]) & 0xFFFFFC00u) | (cbid + 2));
        p3 = __uint_as_float((__float_as_uint(acc1[3]) & 0xFFFFFC00u) | (cbid + 3));
        bt1 = fmaxf(bt1, fmaxf(p0, p1));
        bt1 = fmaxf(bt1, fmaxf(p2, p3));

        a0 = a0n; a1 = a1n; e2v = e2n;
    }

    // ---- in-wave reduce over quads: every lane ends with its row's winner ----
    bt0 = fmaxf(bt0, __shfl_xor(bt0, 16, 64));
    bt1 = fmaxf(bt1, __shfl_xor(bt1, 16, 64));
    bt0 = fmaxf(bt0, __shfl_xor(bt0, 32, 64));
    bt1 = fmaxf(bt1, __shfl_xor(bt1, 32, 64));
    const int kA = (int)(__float_as_uint(bt0) & 1023u);   // row row0+lc
    const int kB = (int)(__float_as_uint(bt1) & 1023u);   // row row0+16+lc

    if (lane < 16) atomicAdd(&hist[kA], 1);
    else if (lane < 32) atomicAdd(&hist[kB], 1);

    // ---- per-wave epilogue, no barrier: x from the b-frags (registers),
    // e from the LDS codebook, q = bf16 codebook row.
    float ls = 0.f;
#pragma unroll
    for (int h = 0; h < 2; ++h) {
        const int k = h ? kB : kA;
        const size_t row = row0 + h * 16 + lc;
        const short8 xv0 = h ? b10 : b00;
        const short8 xv1 = h ? b11 : b01;
        const char* ep = cb + (k >> 4) * 2048 + quad * 256 + (k & 15) * 16;
        short8 ev0 = *(const short8*)(ep);            // d = quad*8..+8 (ks0)
        short8 ev1 = *(const short8*)(ep + 1024);     // d = 32+quad*8..+8 (ks1)
        float4 qa, qb, qc, qd;
        float e0, dd;
        e0 = b2f(ev0[0]); dd = e0 - b2f(xv0[0]); ls = fmaf(dd, dd, ls); qa.x = e0;
        e0 = b2f(ev0[1]); dd = e0 - b2f(xv0[1]); ls = fmaf(dd, dd, ls); qa.y = e0;
        e0 = b2f(ev0[2]); dd = e0 - b2f(xv0[2]); ls = fmaf(dd, dd, ls); qa.z = e0;
        e0 = b2f(ev0[3]); dd = e0 - b2f(xv0[3]); ls = fmaf(dd, dd, ls); qa.w = e0;
        e0 = b2f(ev0[4]); dd = e0 - b2f(xv0[4]); ls = fmaf(dd, dd, ls); qb.x = e0;
        e0 = b2f(ev0[5]); dd = e0 - b2f(xv0[5]); ls = fmaf(dd, dd, ls); qb.y = e0;
        e0 = b2f(ev0[6]); dd = e0 - b2f(xv0[6]); ls = fmaf(dd, dd, ls); qb.z = e0;
        e0 = b2f(ev0[7]); dd = e0 - b2f(xv0[7]); ls = fmaf(dd, dd, ls); qb.w = e0;
        e0 = b2f(ev1[0]); dd = e0 - b2f(xv1[0]); ls = fmaf(dd, dd, ls); qc.x = e0;
        e0 = b2f(ev1[1]); dd = e0 - b2f(xv1[1]); ls = fmaf(dd, dd, ls); qc.y = e0;
        e0 = b2f(ev1[2]); dd = e0 - b2f(xv1[2]); ls = fmaf(dd, dd, ls); qc.z = e0;
        e0 = b2f(ev1[3]); dd = e0 - b2f(xv1[3]); ls = fmaf(dd, dd, ls); qc.w = e0;
        e0 = b2f(ev1[4]); dd = e0 - b2f(xv1[4]); ls = fmaf(dd, dd, ls); qd.x = e0;
        e0 = b2f(ev1[5]); dd = e0 - b2f(xv1[5]); ls = fmaf(dd, dd, ls); qd.y = e0;
        e0 = b2f(ev1[6]); dd = e0 - b2f(xv1[6]); ls = fmaf(dd, dd, ls); qd.z = e0;
        e0 = b2f(ev1[7]); dd = e0 - b2f(xv1[7]); ls = fmaf(dd, dd, ls); qd.w = e0;
        float* qp = q + row * D + quad * 8;
        *(float4*)(qp) = qa;
        *(float4*)(qp + 4) = qb;
        *(float4*)(qp + 32) = qc;
        *(float4*)(qp + 36) = qd;
    }

    // ---- block loss reduction (only remaining end barrier) ----
    for (int off = 32; off > 0; off >>= 1) ls += __shfl_down(ls, off, 64);
    if (lane == 0) redL[wave] = ls;
    __syncthreads();
    if (tid == 0) {
        float L = 0.f;
#pragma unroll
        for (int i = 0; i < 16; ++i) L += redL[i];
        wavesum[blockIdx.x] = L;
    }
}

__global__ __launch_bounds__(1024) void finalize_kernel(const int* __restrict__ hist,
                                                        const float* __restrict__ wavesum,
                                                        float* __restrict__ out) {
    __shared__ float redH[16], redL[16];
    int tid = threadIdx.x;
    float p = (float)hist[tid] * (1.0f / (float)NROWS);
    float term = p * logf(p + 1e-10f);
    float ls = (tid < 256) ? wavesum[tid] : 0.f;
    for (int off = 32; off > 0; off >>= 1) {
        term += __shfl_down(term, off, 64);
        ls += __shfl_down(ls, off, 64);
    }
    int lane = tid & 63, wid = tid >> 6;
    if (lane == 0) { redH[wid] = term; redL[wid] = ls; }
    __syncthreads();
    if (tid == 0) {
        float H = 0.f, L = 0.f;
#pragma unroll
        for (int i = 0; i < 16; ++i) { H += redH[i]; L += redL[i]; }
        out[(size_t)NROWS * D + 0] = 2.0f * (L / (float)(NROWS * D));
        out[(size_t)NROWS * D + 1] = expf(-H);
    }
}

extern "C" void kernel_launch(void* const* d_in, const int* in_sizes, int n_in,
                              void* d_out, int out_size, void* d_ws, size_t ws_size,
                              hipStream_t stream) {
    const float* X = (const float*)d_in[0];   // [64,2048,64] fp32
    const float* E = (const float*)d_in[1];   // [64,1024]   fp32
    float* out = (float*)d_out;

    char* w = (char*)d_ws;
    unsigned short* ehT = (unsigned short*)(w + 0);
    float* e2g          = (float*)(w + 131072);
    int* hist           = (int*)(w + 135168);
    float* wavesum      = (float*)(w + 139264);

    prep_kernel<<<16, 256, 0, stream>>>(E, ehT, e2g, hist);
    score_kernel<<<NROWS / 512, 1024, 135168, stream>>>(X, ehT, e2g, hist, wavesum, out);
    finalize_kernel<<<1, 1024, 0, stream>>>(hist, wavesum, out);
}